// Round 8
// baseline (209.681 us; speedup 1.0000x reference)
//
#include <hip/hip_runtime.h>

#define Bsz 512
#define Nn  128
#define Dd  256
#define Tt  512

typedef __attribute__((ext_vector_type(8))) short short8;
typedef __attribute__((ext_vector_type(4))) float f32x4;

__device__ __forceinline__ ushort f2bf(float f) {
    union { float f; unsigned u; } v; v.f = f;
    unsigned r = v.u + 0x7fffu + ((v.u >> 16) & 1u);  // RNE
    return (ushort)(r >> 16);
}
__device__ __forceinline__ unsigned pk2(float a, float b) {
    return (unsigned)f2bf(a) | ((unsigned)f2bf(b) << 16);
}
__device__ __forceinline__ float bf2f(ushort u) {
    union { unsigned u; float f; } v; v.u = (unsigned)u << 16; return v.f;
}

// LDS swizzle on 256B rows: bank-group = 16B-granule mod 8; g' = g ^ (row&7)
// permutes groups per row. Needed for row-parallel column reads (K1 matvecs
// would be 64-way conflicted without it). Applied to every access.
__device__ __forceinline__ ushort* AP(ushort* base, int row, int col) {
    return base + row * 128 + (((col >> 3) ^ (row & 7)) << 3) + (col & 7);
}
__device__ __forceinline__ uint* XP(uint* base, int row, int col) {
    return base + row * 64 + (((col >> 2) ^ (row & 7)) << 2) + (col & 3);
}

// ============== K1: per-batch scalar chain -> u[128], rowc[128] ============
// 512 blocks x 256 thr, ~35 KB LDS (2 blocks/CU). Streaming + TLP-hidden.
__global__ __launch_bounds__(256, 2) void chainK(
    const float* __restrict__ x, const float* __restrict__ adj,
    const int* __restrict__ head, const float* __restrict__ lin_w,
    const float* __restrict__ bias,
    float* __restrict__ uws, float* __restrict__ rws)
{
    const int t = threadIdx.x, b = blockIdx.x;
    __shared__ __align__(16) uint raw[8192];          // 32 KB: partx -> adjB
    __shared__ float dotS[Nn], ttS[Nn], disS[Nn], maskS[Nn], alphaS[Nn];
    __shared__ int   flags[Nn];
    __shared__ int   nuniq;
    __shared__ float cutS;

    float*  partx = (float*)raw;
    ushort* adjB  = (ushort*)raw;

    const float bias0 = bias[0];
    if (t < Nn) flags[t] = 0;
    if (t == 0) { nuniq = 0; cutS = 0.f; }
    const int hv0 = head[(size_t)b * Tt + t];
    const int hv1 = head[(size_t)b * Tt + 256 + t];

    // ---- X phase: dot partials (coalesced float4; swizzled partx store) ----
    {
        const int rep = t >> 6, d4 = t & 63;
        const float4 w4 = ((const float4*)lin_w)[d4];
        const float* xb = x + (size_t)b * Nn * Dd + 4 * d4;
#pragma unroll
        for (int i = 0; i < 32; ++i) {
            int k = rep * 32 + i;
            float4 v = *(const float4*)(xb + (size_t)k * Dd);
            float p = v.x * w4.x + v.y * w4.y + v.z * w4.z + v.w * w4.w;
            int gs = (d4 >> 2) ^ (k & 7);
            partx[k * 64 + (gs << 2) + (d4 & 3)] = p;
        }
    }
    __syncthreads();                                   // B1
    {   // ---- reduce dot (2 thr/node) ----
        const int k = t >> 1, h = t & 1;
        float s = 0.f;
#pragma unroll
        for (int jj = 0; jj < 8; ++jj) {
            int Gs = (h * 8 + jj) ^ (k & 7);
            f32x4 q = *(const f32x4*)&partx[k * 64 + 4 * Gs];
            s += q[0] + q[1] + q[2] + q[3];
        }
        s += __shfl_xor(s, 1);
        if (h == 0) dotS[k] = s;
        flags[hv0] = 1; flags[hv1] = 1;
    }
    __syncthreads();                                   // B2: partx dead
    {   // ---- stage adj -> bf16 (swizzled) ----
        const float* adjb = adj + (size_t)b * Nn * Nn;
#pragma unroll
        for (int i = 0; i < 16; ++i) {
            int f = t + 256 * i;
            int rr = f >> 5, c = (f & 31) * 4;
            float4 v = *(const float4*)&adjb[(size_t)rr * Nn + c];
            uint2 w2; w2.x = pk2(v.x, v.y); w2.y = pk2(v.z, v.w);
            *(uint2*)AP(adjB, rr, c) = w2;
        }
    }
    __syncthreads();                                   // B3

    const int row = t >> 1, h = t & 1;
    {   // ---- row sums (2 thr/row) ----
        float s = 0.f;
#pragma unroll
        for (int j = 0; j < 8; ++j) {
            short8 a = *(const short8*)AP(adjB, row, h * 64 + j * 8);
#pragma unroll
            for (int jj = 0; jj < 8; ++jj) s += bf2f((ushort)a[jj]);
        }
        s += __shfl_xor(s, 1);
        if (h == 0) {
            maskS[row] = (s > 0.f) ? 1.f : 0.f;
            float dis = 1.f / sqrtf(fmaxf(s + 1.f, 1.f));
            disS[row] = dis;
            ttS[row]  = dis * dotS[row];
        }
    }
    __syncthreads();                                   // B4
    {   // ---- matvec adj*tt -> alpha ----
        float s = 0.f;
#pragma unroll
        for (int j = 0; j < 8; ++j) {
            short8 a = *(const short8*)AP(adjB, row, h * 64 + j * 8);
            f32x4 t0 = *(const f32x4*)&ttS[h * 64 + j * 8];
            f32x4 t1 = *(const f32x4*)&ttS[h * 64 + j * 8 + 4];
#pragma unroll
            for (int jj = 0; jj < 4; ++jj) {
                s += bf2f((ushort)a[jj])     * t0[jj];
                s += bf2f((ushort)a[4 + jj]) * t1[jj];
            }
        }
        s += __shfl_xor(s, 1);
        if (h == 0) {
            float o = maskS[row] * disS[row] * (s + ttS[row]) + bias0;
            alphaS[row] = 1.f / (1.f + expf(-o * o));
            atomicAdd(&nuniq, flags[row]);
        }
    }
    __syncthreads();                                   // B5
    {   // ---- k-th largest rank select ----
        int nu = nuniq;
        if (nu > 1) {
            float an = alphaS[row];
            int cg = 0, ce = 0;
#pragma unroll
            for (int v = 0; v < 16; ++v) {
                f32x4 A = *(const f32x4*)&alphaS[h * 64 + 4 * v];
#pragma unroll
                for (int jj = 0; jj < 4; ++jj) { cg += (A[jj] > an); ce += (A[jj] == an); }
            }
            cg += __shfl_xor(cg, 1);
            ce += __shfl_xor(ce, 1);
            if (h == 0) {
                int idx = (int)ceilf((float)nu * 0.1f);
                if (idx > Nn - 1) idx = Nn - 1;
                if (cg <= idx && idx < cg + ce) cutS = an;  // benign same-value race
            }
        }
    }
    __syncthreads();                                   // B6
    {   // ---- matvec adj*u -> rowc; write u, rowc ----
        const float cut = cutS;
        float s = 0.f;
#pragma unroll
        for (int j = 0; j < 8; ++j) {
            short8 a = *(const short8*)AP(adjB, row, h * 64 + j * 8);
            f32x4 A0 = *(const f32x4*)&alphaS[h * 64 + j * 8];
            f32x4 A1 = *(const f32x4*)&alphaS[h * 64 + j * 8 + 4];
            f32x4 D0 = *(const f32x4*)&disS[h * 64 + j * 8];
            f32x4 D1 = *(const f32x4*)&disS[h * 64 + j * 8 + 4];
#pragma unroll
            for (int jj = 0; jj < 4; ++jj) {
                s += bf2f((ushort)a[jj])     * fmaxf(A0[jj] + 1e-7f - cut, 0.f) * D0[jj];
                s += bf2f((ushort)a[4 + jj]) * fmaxf(A1[jj] + 1e-7f - cut, 0.f) * D1[jj];
            }
        }
        s += __shfl_xor(s, 1);
        if (h == 0) {
            float ur   = fmaxf(alphaS[row] + 1e-7f - cut, 0.f) * disS[row];
            float rsum = maskS[row] * disS[row] * (ur + s);
            rws[(size_t)b * Nn + row] = maskS[row] * disS[row] / fmaxf(rsum, 1e-12f);
            uws[(size_t)b * Nn + row] = ur;
        }
    }
}

// ============== K2: pure GEMM pipeline (no scalar chain) ===================
// 512 blocks x 1024 thr, ~131 KB LDS (1 block/CU). 4 barriers.
__global__ __launch_bounds__(1024, 4) void gemmK(
    const float* __restrict__ x, const float* __restrict__ adj,
    const float* __restrict__ uws, const float* __restrict__ rws,
    float* __restrict__ emb, float* __restrict__ nadj)
{
    const int t = threadIdx.x, b = blockIdx.x;
    __shared__ __align__(16) ushort adjR[Nn * 128];   // 32 KB (-> PT after G2)
    __shared__ __align__(16) ushort stR[Nn * 128];    // 32 KB
    __shared__ __align__(16) uint   xtR0[Nn * 64];    // 32 KB  x bf16 pairs d 0..127
    __shared__ __align__(16) uint   xtR1[Nn * 64];    // 32 KB  d 128..255
    __shared__ float uS[Nn], rowcS[Nn];

    const int lane = t & 63, w = t >> 6;
    const int l15 = lane & 15, quad = lane >> 4;
    const int mrow  = (w & 7) * 16;
    const int nhalf = (w >> 3) * 64;
    const int xrow = t & 127, kq0 = t >> 7;

    float uv = 0.f, rv = 0.f;
    if (t < Nn) { uv = uws[(size_t)b * Nn + t]; rv = rws[(size_t)b * Nn + t]; }

    // ---- read burst: x + adj, pack to LDS (no dot, no shuffles) ----
    float e0[8], g0[8], e1[8], g1[8];
    {
        const float* xb = x + (size_t)b * Nn * Dd + xrow;
#pragma unroll
        for (int k = 0; k < 8; ++k) e0[k] = xb[(size_t)(8 * kq0 + k) * Dd];
#pragma unroll
        for (int k = 0; k < 8; ++k) g0[k] = xb[(size_t)(64 + 8 * kq0 + k) * Dd];
#pragma unroll
        for (int k = 0; k < 8; ++k) e1[k] = xb[(size_t)(8 * kq0 + k) * Dd + 128];
#pragma unroll
        for (int k = 0; k < 8; ++k) g1[k] = xb[(size_t)(64 + 8 * kq0 + k) * Dd + 128];
    }
    float4 av0, av1, av2, av3;
    {
        const float4* adjb = (const float4*)(adj + (size_t)b * Nn * Nn);
        av0 = adjb[t]; av1 = adjb[t + 1024]; av2 = adjb[t + 2048]; av3 = adjb[t + 3072];
    }
    {
        uint4 q;
        q.x = pk2(e0[0], e0[1]); q.y = pk2(e0[2], e0[3]);
        q.z = pk2(e0[4], e0[5]); q.w = pk2(e0[6], e0[7]);
        *(uint4*)XP(xtR0, xrow, 4 * kq0) = q;
        q.x = pk2(g0[0], g0[1]); q.y = pk2(g0[2], g0[3]);
        q.z = pk2(g0[4], g0[5]); q.w = pk2(g0[6], g0[7]);
        *(uint4*)XP(xtR0, xrow, 4 * kq0 + 32) = q;
        q.x = pk2(e1[0], e1[1]); q.y = pk2(e1[2], e1[3]);
        q.z = pk2(e1[4], e1[5]); q.w = pk2(e1[6], e1[7]);
        *(uint4*)XP(xtR1, xrow, 4 * kq0) = q;
        q.x = pk2(g1[0], g1[1]); q.y = pk2(g1[2], g1[3]);
        q.z = pk2(g1[4], g1[5]); q.w = pk2(g1[6], g1[7]);
        *(uint4*)XP(xtR1, xrow, 4 * kq0 + 32) = q;
    }
    {
        float4 v; int f, rr2, c; uint2 w2;
        v = av0; f = t;        rr2 = f >> 5; c = (f & 31) * 4; w2.x = pk2(v.x, v.y); w2.y = pk2(v.z, v.w); *(uint2*)AP(adjR, rr2, c) = w2;
        v = av1; f = t + 1024; rr2 = f >> 5; c = (f & 31) * 4; w2.x = pk2(v.x, v.y); w2.y = pk2(v.z, v.w); *(uint2*)AP(adjR, rr2, c) = w2;
        v = av2; f = t + 2048; rr2 = f >> 5; c = (f & 31) * 4; w2.x = pk2(v.x, v.y); w2.y = pk2(v.z, v.w); *(uint2*)AP(adjR, rr2, c) = w2;
        v = av3; f = t + 3072; rr2 = f >> 5; c = (f & 31) * 4; w2.x = pk2(v.x, v.y); w2.y = pk2(v.z, v.w); *(uint2*)AP(adjR, rr2, c) = w2;
    }
    if (t < Nn) { uS[t] = uv; rowcS[t] = rv; }
    __syncthreads();                                   // B1

    // ---- build ST[m][k] = rowc_k*(adj[k][m]+delta)*u_m (bf16, swizzled) ----
    {
        const int m = t & 127, sl = t >> 7, k0 = sl * 16;
        const float um = uS[m];
        float vv[16];
#pragma unroll
        for (int j = 0; j < 16; ++j) {
            int k = k0 + j;
            vv[j] = rowcS[k] * (bf2f(*AP(adjR, k, m)) + ((k == m) ? 1.f : 0.f)) * um;
        }
        uint4 p0, p1;
        p0.x = pk2(vv[0],  vv[1]);  p0.y = pk2(vv[2],  vv[3]);
        p0.z = pk2(vv[4],  vv[5]);  p0.w = pk2(vv[6],  vv[7]);
        p1.x = pk2(vv[8],  vv[9]);  p1.y = pk2(vv[10], vv[11]);
        p1.z = pk2(vv[12], vv[13]); p1.w = pk2(vv[14], vv[15]);
        *(uint4*)AP(stR, m, k0)     = p0;
        *(uint4*)AP(stR, m, k0 + 8) = p1;
    }
    __syncthreads();                                   // B2

    f32x4 acc[4];
    // ---- G2: P = adj * S ----
#pragma unroll
    for (int nt = 0; nt < 4; ++nt) acc[nt] = (f32x4){0.f, 0.f, 0.f, 0.f};
#pragma unroll
    for (int k0 = 0; k0 < 128; k0 += 32) {
        short8 a0 = *(const short8*)AP(adjR, mrow + l15, k0 + quad * 8);
#pragma unroll
        for (int nt = 0; nt < 4; ++nt) {
            short8 bf = *(const short8*)AP(stR, nhalf + nt * 16 + l15, k0 + quad * 8);
            acc[nt] = __builtin_amdgcn_mfma_f32_16x16x32_bf16(a0, bf, acc[nt], 0, 0, 0);
        }
    }
    __syncthreads();                                   // B3: adj bf16 dead

    // ---- write P^T (bf16) into adjR region ----
#pragma unroll
    for (int nt = 0; nt < 4; ++nt) {
        int j    = nhalf + nt * 16 + l15;
        int mcol = mrow + quad * 4;
        uint2 w2;
        w2.x = pk2(acc[nt][0], acc[nt][1]);
        w2.y = pk2(acc[nt][2], acc[nt][3]);
        *(uint2*)AP(adjR, j, mcol) = w2;
    }
    __syncthreads();                                   // B4

    // ---- G3: nadj = S^T P ----
#pragma unroll
    for (int nt = 0; nt < 4; ++nt) acc[nt] = (f32x4){0.f, 0.f, 0.f, 0.f};
#pragma unroll
    for (int k0 = 0; k0 < 128; k0 += 32) {
        short8 a0 = *(const short8*)AP(stR, mrow + l15, k0 + quad * 8);
#pragma unroll
        for (int nt = 0; nt < 4; ++nt) {
            short8 bf = *(const short8*)AP(adjR, nhalf + nt * 16 + l15, k0 + quad * 8);
            acc[nt] = __builtin_amdgcn_mfma_f32_16x16x32_bf16(a0, bf, acc[nt], 0, 0, 0);
        }
    }
#pragma unroll
    for (int nt = 0; nt < 4; ++nt)
#pragma unroll
        for (int rr2 = 0; rr2 < 4; ++rr2) {
            int row = mrow + quad * 4 + rr2;
            int col = nhalf + nt * 16 + l15;
            nadj[((size_t)b * Nn + row) * Nn + col] = acc[nt][rr2];
        }

    // ---- emb = S^T x from xtR0/xtR1 ----
    const int dcb = (w >> 3) * 64;
    f32x4 accE[4];
#pragma unroll
    for (int nt = 0; nt < 4; ++nt) accE[nt] = (f32x4){0.f, 0.f, 0.f, 0.f};
#pragma unroll
    for (int ks = 0; ks < 4; ++ks) {
        short8 aE = *(const short8*)AP(stR, mrow + l15, ks * 32 + quad * 8);
#pragma unroll
        for (int nt = 0; nt < 4; ++nt) {
            short8 bf = *(const short8*)XP(xtR0, dcb + nt * 16 + l15, ks * 16 + quad * 4);
            accE[nt] = __builtin_amdgcn_mfma_f32_16x16x32_bf16(aE, bf, accE[nt], 0, 0, 0);
        }
    }
#pragma unroll
    for (int nt = 0; nt < 4; ++nt)
#pragma unroll
        for (int rr2 = 0; rr2 < 4; ++rr2) {
            int row = mrow + quad * 4 + rr2;
            int col = dcb + nt * 16 + l15;
            emb[((size_t)b * Nn + row) * Dd + col] = accE[nt][rr2];
        }

#pragma unroll
    for (int nt = 0; nt < 4; ++nt) accE[nt] = (f32x4){0.f, 0.f, 0.f, 0.f};
#pragma unroll
    for (int ks = 0; ks < 4; ++ks) {
        short8 aE = *(const short8*)AP(stR, mrow + l15, ks * 32 + quad * 8);
#pragma unroll
        for (int nt = 0; nt < 4; ++nt) {
            short8 bf = *(const short8*)XP(xtR1, dcb + nt * 16 + l15, ks * 16 + quad * 4);
            accE[nt] = __builtin_amdgcn_mfma_f32_16x16x32_bf16(aE, bf, accE[nt], 0, 0, 0);
        }
    }
#pragma unroll
    for (int nt = 0; nt < 4; ++nt)
#pragma unroll
        for (int rr2 = 0; rr2 < 4; ++rr2) {
            int row = mrow + quad * 4 + rr2;
            int col = 128 + dcb + nt * 16 + l15;
            emb[((size_t)b * Nn + row) * Dd + col] = accE[nt][rr2];
        }
}

extern "C" void kernel_launch(void* const* d_in, const int* in_sizes, int n_in,
                              void* d_out, int out_size, void* d_ws, size_t ws_size,
                              hipStream_t stream)
{
    const float* x     = (const float*)d_in[0];
    const float* adj   = (const float*)d_in[1];
    const int*   head  = (const int*)d_in[2];
    const float* lin_w = (const float*)d_in[3];
    const float* bias  = (const float*)d_in[4];

    float* emb  = (float*)d_out;                 // [B,N,D]
    float* nadj = emb + (size_t)Bsz * Nn * Dd;   // [B,N,N]

    float* uws = (float*)d_ws;                   // [B,N]
    float* rws = uws + (size_t)Bsz * Nn;         // [B,N]

    chainK<<<Bsz, 256, 0, stream>>>(x, adj, head, lin_w, bias, uws, rws);
    gemmK<<<Bsz, 1024, 0, stream>>>(x, adj, uws, rws, emb, nadj);
}

// Round 9
// 200.615 us; speedup vs baseline: 1.0452x; 1.0452x over previous
//
#include <hip/hip_runtime.h>

#define Bsz 512
#define Nn  128
#define Dd  256
#define Tt  512

typedef __attribute__((ext_vector_type(8))) short short8;
typedef __attribute__((ext_vector_type(4))) float f32x4;

__device__ __forceinline__ ushort f2bf(float f) {
    union { float f; unsigned u; } v; v.f = f;
    unsigned r = v.u + 0x7fffu + ((v.u >> 16) & 1u);  // RNE
    return (ushort)(r >> 16);
}
__device__ __forceinline__ unsigned pk2(float a, float b) {
    return (unsigned)f2bf(a) | ((unsigned)f2bf(b) << 16);
}
__device__ __forceinline__ float bf2f(ushort u) {
    union { unsigned u; float f; } v; v.u = (unsigned)u << 16; return v.f;
}

// v9 = v2 (session-best, 198.85) + aE register-hoist in the emb GEMM.
// Session conclusion: per-batch barrier chain ~36us is the floor for this
// structure; cross-batch overlap attempts all defeated (reg-prefetch ->
// spill [v3/v5], co-resident blocks -> lockstep [v2==v4], kernel split ->
// launch+re-read overhead [v8]). Conflict counts at wide-read floor [v7].
__global__ __launch_bounds__(1024, 8) void mega(
    const float* __restrict__ x, const float* __restrict__ adj,
    const int* __restrict__ head, const float* __restrict__ lin_w,
    const float* __restrict__ bias,
    float* __restrict__ emb, float* __restrict__ nadj)
{
    const int b = blockIdx.x, t = threadIdx.x;
    __shared__ __align__(16) ushort adjB[Nn][136];   // 34816 B (-> PT -> xTp)
    __shared__ __align__(16) ushort STl[Nn][136];    // 34816 B
    __shared__ float ttS[Nn], disS[Nn], maskS[Nn], alphaS[Nn], uS[Nn], rowcS[Nn];
    __shared__ float dotL[Nn];
    __shared__ int   flags[Nn];
    __shared__ int   nuniq;
    __shared__ float cutS;

    const float bias0 = bias[0];
    if (t < Nn) flags[t] = 0;
    if (t == 0) { nuniq = 0; cutS = 0.f; }

    // ---- overlapped read burst: waves 0-7 x-dot (+head), waves 8-15 adj ----
    int hv = 0;
    if (t < 512) {
        hv = head[(size_t)b * Tt + t];
        const int dr = t >> 2, dh = t & 3;
        const float4* xr = (const float4*)(x + ((size_t)b * Nn + dr) * Dd + dh * 64);
        const float4* wr = (const float4*)(lin_w + dh * 64);
        float p = 0.f;
#pragma unroll
        for (int i = 0; i < 16; ++i) {
            float4 v = xr[i], w4 = wr[i];
            p += v.x * w4.x + v.y * w4.y + v.z * w4.z + v.w * w4.w;
        }
        p += __shfl_xor(p, 1, 64);
        p += __shfl_xor(p, 2, 64);
        if (dh == 0) dotL[dr] = p;
    } else {
        const int t2 = t - 512;
        const float* adjb = adj + (size_t)b * Nn * Nn;
#pragma unroll
        for (int i = 0; i < 8; ++i) {
            int f = t2 + 512 * i;
            int rr = f >> 5, c = (f & 31) * 4;
            float4 v = *(const float4*)&adjb[(size_t)rr * Nn + c];
            uint2 w2; w2.x = pk2(v.x, v.y); w2.y = pk2(v.z, v.w);
            *(uint2*)&adjB[rr][c] = w2;
        }
    }
    __syncthreads();                                           // B1

    if (t < Tt) flags[hv] = 1;   // consumed after B2

    const int r = t >> 3, seg = t & 7;
    {   // ---- row sums (8 lanes/row, shuffle reduce) ----
        short8 a0 = *(const short8*)&adjB[r][seg * 16];
        short8 a1 = *(const short8*)&adjB[r][seg * 16 + 8];
        float s = 0.f;
#pragma unroll
        for (int j = 0; j < 8; ++j) s += bf2f((ushort)a0[j]) + bf2f((ushort)a1[j]);
        s += __shfl_xor(s, 1, 64);
        s += __shfl_xor(s, 2, 64);
        s += __shfl_xor(s, 4, 64);
        if (seg == 0) {
            maskS[r] = (s > 0.f) ? 1.f : 0.f;
            float dis = 1.f / sqrtf(fmaxf(s + 1.f, 1.f));
            disS[r] = dis;
            ttS[r]  = dis * dotL[r];
        }
    }
    __syncthreads();                                           // B2

    {   // ---- matvec adj*tt -> alpha ----
        short8 a0 = *(const short8*)&adjB[r][seg * 16];
        short8 a1 = *(const short8*)&adjB[r][seg * 16 + 8];
        float s = 0.f;
#pragma unroll
        for (int j = 0; j < 8; ++j) {
            s += bf2f((ushort)a0[j]) * ttS[seg * 16 + j];
            s += bf2f((ushort)a1[j]) * ttS[seg * 16 + 8 + j];
        }
        s += __shfl_xor(s, 1, 64);
        s += __shfl_xor(s, 2, 64);
        s += __shfl_xor(s, 4, 64);
        if (seg == 0) {
            float o = maskS[r] * disS[r] * (s + ttS[r]) + bias0;
            alphaS[r] = 1.f / (1.f + expf(-o * o));
            atomicAdd(&nuniq, flags[r]);
        }
    }
    __syncthreads();                                           // B3

    if (t < Nn) {  // exact k-th largest (rank select; ties like sort)
        int nu = nuniq;
        if (nu > 1) {
            int idx = (int)ceilf((float)nu * 0.1f);
            if (idx > Nn - 1) idx = Nn - 1;
            float an = alphaS[t];
            int cg = 0, ce = 0;
            for (int j = 0; j < Nn; ++j) {
                float aj = alphaS[j];
                cg += (aj > an); ce += (aj == an);
            }
            if (cg <= idx && idx < cg + ce) cutS = an;  // benign same-value race
        }
    }
    __syncthreads();                                           // B4
    if (t < Nn) uS[t] = fmaxf(alphaS[t] + 1e-7f - cutS, 0.f) * disS[t];
    __syncthreads();                                           // B5

    {   // ---- matvec adj*u -> rowc (row L1; all terms >= 0) ----
        short8 a0 = *(const short8*)&adjB[r][seg * 16];
        short8 a1 = *(const short8*)&adjB[r][seg * 16 + 8];
        float s = 0.f;
#pragma unroll
        for (int j = 0; j < 8; ++j) {
            s += bf2f((ushort)a0[j]) * uS[seg * 16 + j];
            s += bf2f((ushort)a1[j]) * uS[seg * 16 + 8 + j];
        }
        s += __shfl_xor(s, 1, 64);
        s += __shfl_xor(s, 2, 64);
        s += __shfl_xor(s, 4, 64);
        if (seg == 0) {
            float rsum = maskS[r] * disS[r] * (uS[r] + s);
            rowcS[r]   = maskS[r] * disS[r] / fmaxf(rsum, 1e-12f);
        }
    }
    __syncthreads();                                           // B6

    // ---- build ST[m][k] = rowc_k*(adj[k][m]+delta)*u_m (bf16, in LDS) ----
    {
        const int m = t & 127, sl = t >> 7, k0 = sl * 16;
        const float um = uS[m];
        float vv[16];
#pragma unroll
        for (int j = 0; j < 16; ++j) {
            int k = k0 + j;
            vv[j] = rowcS[k] * (bf2f(adjB[k][m]) + ((k == m) ? 1.f : 0.f)) * um;
        }
        uint4 p0, p1;
        p0.x = pk2(vv[0],  vv[1]);  p0.y = pk2(vv[2],  vv[3]);
        p0.z = pk2(vv[4],  vv[5]);  p0.w = pk2(vv[6],  vv[7]);
        p1.x = pk2(vv[8],  vv[9]);  p1.y = pk2(vv[10], vv[11]);
        p1.z = pk2(vv[12], vv[13]); p1.w = pk2(vv[14], vv[15]);
        *(uint4*)&STl[m][k0]     = p0;
        *(uint4*)&STl[m][k0 + 8] = p1;
    }
    __syncthreads();                                           // B7

    // ---- wave tiling: 16 waves, each a 16x64 C tile ----
    const int lane = t & 63, w = t >> 6;
    const int l15 = lane & 15, quad = lane >> 4;
    const int mrow  = (w & 7) * 16;
    const int nhalf = (w >> 3) * 64;
    f32x4 acc[4];

    // ---- G2: P = adj * S ----
#pragma unroll
    for (int nt = 0; nt < 4; ++nt) acc[nt] = (f32x4){0.f, 0.f, 0.f, 0.f};
#pragma unroll
    for (int k0 = 0; k0 < 128; k0 += 32) {
        short8 a0 = *(const short8*)&adjB[mrow + l15][k0 + quad * 8];
#pragma unroll
        for (int nt = 0; nt < 4; ++nt) {
            short8 bf = *(const short8*)&STl[nhalf + nt * 16 + l15][k0 + quad * 8];
            acc[nt] = __builtin_amdgcn_mfma_f32_16x16x32_bf16(a0, bf, acc[nt], 0, 0, 0);
        }
    }
    __syncthreads();                                           // B8: adj bf16 dead

    // ---- write P^T (bf16) into adjB region ----
    ushort (*PT)[136] = (ushort(*)[136])&adjB[0][0];
#pragma unroll
    for (int nt = 0; nt < 4; ++nt) {
        int j    = nhalf + nt * 16 + l15;
        int mcol = mrow + quad * 4;
        uint2 w2;
        w2.x = pk2(acc[nt][0], acc[nt][1]);
        w2.y = pk2(acc[nt][2], acc[nt][3]);
        *(uint2*)&PT[j][mcol] = w2;
    }
    __syncthreads();                                           // B9

    // ---- half0 x prefetch: overlaps G3 + nadj stores, drained at B10 ----
    const int xrow = t & 127, kq0 = t >> 7;     // xrow = d-col, kq0 in 0..7
    float xv0[8], xv1[8];
    {
        const float* xb = x + (size_t)b * Nn * Dd + xrow;
#pragma unroll
        for (int k = 0; k < 8; ++k) xv0[k] = xb[(size_t)(8 * kq0 + k) * Dd];
#pragma unroll
        for (int k = 0; k < 8; ++k) xv1[k] = xb[(size_t)(8 * (kq0 + 8) + k) * Dd];
    }

    // ---- G3: nadj = S^T P ----
#pragma unroll
    for (int nt = 0; nt < 4; ++nt) acc[nt] = (f32x4){0.f, 0.f, 0.f, 0.f};
#pragma unroll
    for (int k0 = 0; k0 < 128; k0 += 32) {
        short8 a0 = *(const short8*)&STl[mrow + l15][k0 + quad * 8];
#pragma unroll
        for (int nt = 0; nt < 4; ++nt) {
            short8 bf = *(const short8*)&PT[nhalf + nt * 16 + l15][k0 + quad * 8];
            acc[nt] = __builtin_amdgcn_mfma_f32_16x16x32_bf16(a0, bf, acc[nt], 0, 0, 0);
        }
    }
#pragma unroll
    for (int nt = 0; nt < 4; ++nt)
#pragma unroll
        for (int rr2 = 0; rr2 < 4; ++rr2) {
            int row = mrow + quad * 4 + rr2;
            int col = nhalf + nt * 16 + l15;
            nadj[((size_t)b * Nn + row) * Nn + col] = acc[nt][rr2];
        }
    __syncthreads();                                           // B10: PT dead

    // ---- emb = S^T x; x staged bf16 k-pairs xTp[d][kp] in dead region ----
    uint (*xTp)[68] = (uint(*)[68])&adjB[0][0];   // 128*68*4 = 34816 B
    const int dcb = (w >> 3) * 64;

    // aE hoist: A-fragments are stable (STl untouched since B7) -> load once
    short8 aE4[4];
#pragma unroll
    for (int ks = 0; ks < 4; ++ks)
        aE4[ks] = *(const short8*)&STl[mrow + l15][ks * 32 + quad * 8];

    // half 0: conflict-free staging writes (uint4 per d-row, lanes vary row)
    {
        uint4 q;
        q.x = pk2(xv0[0], xv0[1]); q.y = pk2(xv0[2], xv0[3]);
        q.z = pk2(xv0[4], xv0[5]); q.w = pk2(xv0[6], xv0[7]);
        *(uint4*)&xTp[xrow][4 * kq0] = q;
        q.x = pk2(xv1[0], xv1[1]); q.y = pk2(xv1[2], xv1[3]);
        q.z = pk2(xv1[4], xv1[5]); q.w = pk2(xv1[6], xv1[7]);
        *(uint4*)&xTp[xrow][4 * (kq0 + 8)] = q;
    }
    __syncthreads();                                           // B11

    // half1 x prefetch: overlaps GEMM h0 + emb h0 stores, drained at B12
    {
        const float* xb = x + (size_t)b * Nn * Dd + 128 + xrow;
#pragma unroll
        for (int k = 0; k < 8; ++k) xv0[k] = xb[(size_t)(8 * kq0 + k) * Dd];
#pragma unroll
        for (int k = 0; k < 8; ++k) xv1[k] = xb[(size_t)(8 * (kq0 + 8) + k) * Dd];
    }

    f32x4 accE[4];
#pragma unroll
    for (int nt = 0; nt < 4; ++nt) accE[nt] = (f32x4){0.f, 0.f, 0.f, 0.f};
#pragma unroll
    for (int ks = 0; ks < 4; ++ks) {
#pragma unroll
        for (int nt = 0; nt < 4; ++nt) {
            short8 bf = *(const short8*)&xTp[dcb + nt * 16 + l15][ks * 16 + quad * 4];
            accE[nt] = __builtin_amdgcn_mfma_f32_16x16x32_bf16(aE4[ks], bf, accE[nt], 0, 0, 0);
        }
    }
#pragma unroll
    for (int nt = 0; nt < 4; ++nt)
#pragma unroll
        for (int rr2 = 0; rr2 < 4; ++rr2) {
            int row = mrow + quad * 4 + rr2;
            int col = dcb + nt * 16 + l15;
            emb[((size_t)b * Nn + row) * Dd + col] = accE[nt][rr2];
        }
    __syncthreads();                                           // B12

    // half 1
    {
        uint4 q;
        q.x = pk2(xv0[0], xv0[1]); q.y = pk2(xv0[2], xv0[3]);
        q.z = pk2(xv0[4], xv0[5]); q.w = pk2(xv0[6], xv0[7]);
        *(uint4*)&xTp[xrow][4 * kq0] = q;
        q.x = pk2(xv1[0], xv1[1]); q.y = pk2(xv1[2], xv1[3]);
        q.z = pk2(xv1[4], xv1[5]); q.w = pk2(xv1[6], xv1[7]);
        *(uint4*)&xTp[xrow][4 * (kq0 + 8)] = q;
    }
    __syncthreads();                                           // B13

#pragma unroll
    for (int nt = 0; nt < 4; ++nt) accE[nt] = (f32x4){0.f, 0.f, 0.f, 0.f};
#pragma unroll
    for (int ks = 0; ks < 4; ++ks) {
#pragma unroll
        for (int nt = 0; nt < 4; ++nt) {
            short8 bf = *(const short8*)&xTp[dcb + nt * 16 + l15][ks * 16 + quad * 4];
            accE[nt] = __builtin_amdgcn_mfma_f32_16x16x32_bf16(aE4[ks], bf, accE[nt], 0, 0, 0);
        }
    }
#pragma unroll
    for (int nt = 0; nt < 4; ++nt)
#pragma unroll
        for (int rr2 = 0; rr2 < 4; ++rr2) {
            int row = mrow + quad * 4 + rr2;
            int col = 128 + dcb + nt * 16 + l15;
            emb[((size_t)b * Nn + row) * Dd + col] = accE[nt][rr2];
        }
}

extern "C" void kernel_launch(void* const* d_in, const int* in_sizes, int n_in,
                              void* d_out, int out_size, void* d_ws, size_t ws_size,
                              hipStream_t stream)
{
    const float* x     = (const float*)d_in[0];
    const float* adj   = (const float*)d_in[1];
    const int*   head  = (const int*)d_in[2];
    const float* lin_w = (const float*)d_in[3];
    const float* bias  = (const float*)d_in[4];

    float* emb  = (float*)d_out;                 // [B,N,D]
    float* nadj = emb + (size_t)Bsz * Nn * Dd;   // [B,N,N]

    mega<<<Bsz, 1024, 0, stream>>>(x, adj, head, lin_w, bias, emb, nadj);
}